// Round 1
// baseline (206.342 us; speedup 1.0000x reference)
//
#include <hip/hip_runtime.h>
#include <stdint.h>

typedef __attribute__((ext_vector_type(8)))  short  short8;
typedef __attribute__((ext_vector_type(8)))  __bf16 bf16x8;
typedef __attribute__((ext_vector_type(16))) float  floatx16;
typedef __attribute__((ext_vector_type(4)))  float  floatx4;

union Frag { short8 s; bf16x8 v; };

// round-to-nearest-even f32 -> bf16 (inputs are finite, no NaN handling needed)
__device__ __forceinline__ short f2bf(float f) {
    union { float f; uint32_t u; } x; x.f = f;
    uint32_t r = x.u + 0x7fffu + ((x.u >> 16) & 1u);
    return (short)(r >> 16);
}

__device__ __forceinline__ float fast_exp2(float x) {
#if __has_builtin(__builtin_amdgcn_exp2f)
    return __builtin_amdgcn_exp2f(x);
#else
    return exp2f(x);
#endif
}

__device__ __forceinline__ float fast_rcp(float x) {
#if __has_builtin(__builtin_amdgcn_rcpf)
    return __builtin_amdgcn_rcpf(x);
#else
    return 1.0f / x;
#endif
}

// y[b] = a0 + sum_k bk[k] * tanh(ck[k,:].z[b,:] + dk[k])
//
// Strategy: D = mfma_32x32x16_bf16(A=s*ck, B=z, C=s*dk) gives
//   D[node][row] = s*(dot + dk),  s = 2*log2(e)
// laid out col(lane&31)=batch row, row(reg-map)=node. Then
//   tanh(t) = 1 - 2/(exp2(s*t)+1)  ->  contribution = bk - 2*bk*rcp(E+1)
// Per lane: 32 in-lane node terms for ONE batch row; one shfl_xor(32)
// merges the complementary node set; coalesced dword stores.
__global__ __launch_bounds__(256) void mave_kernel(
    const float* __restrict__ z,
    const float* __restrict__ a0,
    const float* __restrict__ bk,
    const float* __restrict__ ck,
    const float* __restrict__ dk,
    float* __restrict__ out,
    int ntiles)
{
    const int lane = threadIdx.x & 63;
    const int m    = lane & 31;   // node for A-frag; batch-row-in-tile for B-frag
    const int g    = lane >> 5;
    const float S  = 2.885390081777927f;  // 2*log2(e)

    // A-operand fragments: rows of s*ck (node = m and m+32), k = g*8+e
    Frag af0, af1;
    {
        const float* c0 = ck + m * 16 + g * 8;
        const float* c1 = c0 + 32 * 16;
        #pragma unroll
        for (int e = 0; e < 8; ++e) {
            af0.s[e] = f2bf(c0[e] * S);
            af1.s[e] = f2bf(c1[e] * S);
        }
    }

    // C-operand init = s*dk[node]; per-lane node map (reg&3)+8*(reg>>2)+4*g
    floatx16 cinit0, cinit1;
    float nb0[16], nb1[16];
    #pragma unroll
    for (int r = 0; r < 16; ++r) {
        int n = (r & 3) + 8 * (r >> 2) + 4 * g;
        cinit0[r] = S * dk[n];
        cinit1[r] = S * dk[n + 32];
        nb0[r] = -2.0f * bk[n];
        nb1[r] = -2.0f * bk[n + 32];
    }

    float base = a0[0];
    for (int k = 0; k < 64; ++k) base += bk[k];  // uniform -> scalar ops

    const int wid = (int)((blockIdx.x * blockDim.x + threadIdx.x) >> 6);
    const int nw  = (int)((gridDim.x * blockDim.x) >> 6);

    for (int tile = wid; tile < ntiles; tile += nw) {
        // B-operand: z[row = tile*32 + m][g*8 .. g*8+8) -- 2x dwordx4, wave
        // footprint = 32 rows x 64B = 2KB contiguous
        const float* zp = z + (size_t)(tile * 32 + m) * 16 + g * 8;
        floatx4 z0 = *(const floatx4*)zp;
        floatx4 z1 = *(const floatx4*)(zp + 4);
        Frag bfr;
        bfr.s[0] = f2bf(z0.x); bfr.s[1] = f2bf(z0.y);
        bfr.s[2] = f2bf(z0.z); bfr.s[3] = f2bf(z0.w);
        bfr.s[4] = f2bf(z1.x); bfr.s[5] = f2bf(z1.y);
        bfr.s[6] = f2bf(z1.z); bfr.s[7] = f2bf(z1.w);

        floatx16 acc0 = __builtin_amdgcn_mfma_f32_32x32x16_bf16(af0.v, bfr.v, cinit0, 0, 0, 0);
        floatx16 acc1 = __builtin_amdgcn_mfma_f32_32x32x16_bf16(af1.v, bfr.v, cinit1, 0, 0, 0);

        float y = 0.0f;
        #pragma unroll
        for (int r = 0; r < 16; ++r) {
            float e0 = fast_exp2(acc0[r]);
            float e1 = fast_exp2(acc1[r]);
            y += nb0[r] * fast_rcp(e0 + 1.0f);
            y += nb1[r] * fast_rcp(e1 + 1.0f);
        }
        y += __shfl_xor(y, 32, 64);          // merge complementary node half
        if (g == 0) out[tile * 32 + m] = base + y;
    }
}

extern "C" void kernel_launch(void* const* d_in, const int* in_sizes, int n_in,
                              void* d_out, int out_size, void* d_ws, size_t ws_size,
                              hipStream_t stream) {
    const float* z  = (const float*)d_in[0];
    const float* a0 = (const float*)d_in[1];
    const float* bk = (const float*)d_in[2];
    const float* ck = (const float*)d_in[3];
    const float* dk = (const float*)d_in[4];
    float* out = (float*)d_out;

    const int B      = in_sizes[0] / 16;   // z is [B,16]
    const int ntiles = B / 32;             // 32 batch rows per wave-tile

    dim3 grid(1024), block(256);           // 4096 waves, 16 tiles/wave
    hipLaunchKernelGGL(mave_kernel, grid, block, 0, stream,
                       z, a0, bk, ck, dk, out, ntiles);
}